// Round 13
// baseline (216.995 us; speedup 1.0000x reference)
//
#include <hip/hip_runtime.h>
#include <math.h>

#define LN_TOK 4096
#define NB 2
#define NROWS (NB * LN_TOK)          // 8192
#define DMODEL 256
#define DINNER 1024
#define NHEADS 8
#define GNN 128
#define DPROJ 2312
#define ZSTRIDE 2432                 // padded in-proj N (19*128)
#define EPSF 1e-5f
#define NCHUNK 32
#define CHUNK 128
#define BPAD 64                      // LDS stride for gld16 staging (64-wide panels, pure GEMMs)
#define FPAD 136                     // LDS stride for full-K(128) VALU-staged A (2-way-free banks)
#define BKF 128                      // LDS stride for full-K gld16 B (unpadded; gld16-compatible)
#define TT 16                        // conv tokens per block

typedef unsigned short u16;
typedef unsigned int u32;
typedef __attribute__((ext_vector_type(8))) short shortx8;
typedef __attribute__((ext_vector_type(4))) float floatx4;

__device__ __forceinline__ float sigmoidf_(float v) { return 1.f / (1.f + __expf(-v)); }
__device__ __forceinline__ float siluf_(float v)    { return v / (1.f + __expf(-v)); }
__device__ __forceinline__ float softplusf_(float v){ return v > 20.f ? v : log1pf(__expf(v)); }
__device__ __forceinline__ float b2f(u16 h) { return __uint_as_float(((u32)h) << 16); }
__device__ __forceinline__ u16 f2b(float f) {
    u32 u = __float_as_uint(f);
    u32 r = (u + 0x7fffu + ((u >> 16) & 1u)) >> 16;
    return (u16)r;
}
// async 16B global -> LDS (dest = wave-uniform base + lane*16)
__device__ __forceinline__ void gld16(const void* g, void* l) {
    __builtin_amdgcn_global_load_lds((const __attribute__((address_space(1))) unsigned int*)g,
                                     (__attribute__((address_space(3))) unsigned int*)l, 16, 0, 0);
}

// ------- prologue: LN (blocks 0..8191) + tcast W_in (next 152) + W_out (64) --
__global__ __launch_bounds__(256) void k_prologue(const float* __restrict__ u,
                                                  const float* __restrict__ gam,
                                                  const float* __restrict__ bet,
                                                  u16* __restrict__ xn,
                                                  const float* __restrict__ W_in,
                                                  u16* __restrict__ Wt,
                                                  const float* __restrict__ W_out,
                                                  u16* __restrict__ Wot) {
    __shared__ float smem[64 * 65];
    int bid = blockIdx.x;
    int tid = threadIdx.x;
    if (bid < NROWS) {
        float v = u[(size_t)bid * DMODEL + tid];
        float* s1 = smem;
        float* s2 = smem + 256;
        s1[tid] = v; s2[tid] = v * v;
        __syncthreads();
        for (int off = 128; off > 0; off >>= 1) {
            if (tid < off) { s1[tid] += s1[tid + off]; s2[tid] += s2[tid + off]; }
            __syncthreads();
        }
        float mean = s1[0] * (1.f / DMODEL);
        float var  = s2[0] * (1.f / DMODEL) - mean * mean;
        float r = rsqrtf(var + EPSF);
        xn[(size_t)bid * DMODEL + tid] = f2b((v - mean) * r * gam[tid] + bet[tid]);
    } else {
        const float* in; u16* outp; int R, C, Cp, gx, gy;
        if (bid < NROWS + 152) {
            int q = bid - NROWS;
            in = W_in; outp = Wt; R = DMODEL; C = DPROJ; Cp = ZSTRIDE;
            gx = q % (ZSTRIDE / 64); gy = q / (ZSTRIDE / 64);
        } else {
            int q = bid - NROWS - 152;
            in = W_out; outp = Wot; R = DINNER; C = DMODEL; Cp = DMODEL;
            gx = q % (DMODEL / 64); gy = q / (DMODEL / 64);
        }
        float (*tile)[65] = (float(*)[65])smem;
        int c0 = gx * 64, r0 = gy * 64;
        int tx = tid & 63, ty = tid >> 6;
        for (int rr = ty; rr < 64; rr += 4) {
            int r = r0 + rr, c = c0 + tx;
            tile[rr][tx] = (r < R && c < C) ? in[(size_t)r * C + c] : 0.f;
        }
        __syncthreads();
        for (int cc = ty; cc < 64; cc += 4) {
            int c = c0 + cc, r = r0 + tx;
            if (c < Cp && r < R) outp[(size_t)c * R + r] = f2b(tile[tx][cc]);
        }
    }
}

// ------- bf16 MFMA GEMM (bf16 out), m97-style PURE global_load_lds staging ---
__global__ __launch_bounds__(256) void k_gemm_bf(const u16* __restrict__ A,
                                                 const u16* __restrict__ Bt,
                                                 u16* __restrict__ C,
                                                 int K, int ldc) {
    __shared__ u16 As[128 * BPAD];
    __shared__ u16 Bs[128 * BPAD];
    int tid = threadIdx.x;
    int wave = tid >> 6, lane = tid & 63;
    int wm = wave >> 1, wn = wave & 1;
    int quad = lane >> 4, l16 = lane & 15;
    int m0 = blockIdx.y * 128, n0 = blockIdx.x * 128;
    floatx4 acc[4][4] = {};
    for (int k0 = 0; k0 < K; k0 += 64) {
#pragma unroll
        for (int p = 0; p < 4; p++) {
            int i = p * 256 + tid;
            int row = i >> 3, kk = (i & 7) << 3;
            gld16(&A[(size_t)(m0 + row) * K + k0 + kk], &As[i * 8]);
            gld16(&Bt[(size_t)(n0 + row) * K + k0 + kk], &Bs[i * 8]);
        }
        __syncthreads();
#pragma unroll
        for (int ks = 0; ks < 64; ks += 32) {
            shortx8 af[4], bfr[4];
#pragma unroll
            for (int i = 0; i < 4; i++)
                af[i] = *(shortx8*)&As[(wm * 64 + i * 16 + l16) * BPAD + ks + (quad << 3)];
#pragma unroll
            for (int j = 0; j < 4; j++)
                bfr[j] = *(shortx8*)&Bs[(wn * 64 + j * 16 + l16) * BPAD + ks + (quad << 3)];
#pragma unroll
            for (int i = 0; i < 4; i++)
#pragma unroll
                for (int j = 0; j < 4; j++)
                    acc[i][j] = __builtin_amdgcn_mfma_f32_16x16x32_bf16(af[i], bfr[j], acc[i][j], 0, 0, 0);
        }
        __syncthreads();
    }
#pragma unroll
    for (int i = 0; i < 4; i++) {
        int row = m0 + wm * 64 + i * 16 + quad * 4;
#pragma unroll
        for (int j = 0; j < 4; j++) {
            int col = n0 + wn * 64 + j * 16 + l16;
#pragma unroll
            for (int r = 0; r < 4; r++)
                C[(size_t)(row + r) * ldc + col] = f2b(acc[i][j][r]);
        }
    }
}

// ------- bf16 MFMA GEMM 128x64 tile, fp32 out + residual, pure gld16 ---------
__global__ __launch_bounds__(256) void k_gemm2(const u16* __restrict__ A,
                                               const u16* __restrict__ Bt,
                                               float* __restrict__ C,
                                               int K, int ldc,
                                               const float* __restrict__ addC) {
    __shared__ u16 As[128 * BPAD];
    __shared__ u16 Bs[64 * BPAD];
    int tid = threadIdx.x;
    int wave = tid >> 6, lane = tid & 63;
    int wm = wave >> 1, wn = wave & 1;
    int quad = lane >> 4, l16 = lane & 15;
    int m0 = blockIdx.y * 128, n0 = blockIdx.x * 64;
    floatx4 acc[4][2] = {};
    for (int k0 = 0; k0 < K; k0 += 64) {
#pragma unroll
        for (int p = 0; p < 4; p++) {
            int i = p * 256 + tid;
            int row = i >> 3, kk = (i & 7) << 3;
            gld16(&A[(size_t)(m0 + row) * K + k0 + kk], &As[i * 8]);
        }
#pragma unroll
        for (int p = 0; p < 2; p++) {
            int i = p * 256 + tid;
            int row = i >> 3, kk = (i & 7) << 3;
            gld16(&Bt[(size_t)(n0 + row) * K + k0 + kk], &Bs[i * 8]);
        }
        __syncthreads();
#pragma unroll
        for (int ks = 0; ks < 64; ks += 32) {
            shortx8 af[4], bfr[2];
#pragma unroll
            for (int i = 0; i < 4; i++)
                af[i] = *(shortx8*)&As[(wm * 64 + i * 16 + l16) * BPAD + ks + (quad << 3)];
#pragma unroll
            for (int j = 0; j < 2; j++)
                bfr[j] = *(shortx8*)&Bs[(wn * 32 + j * 16 + l16) * BPAD + ks + (quad << 3)];
#pragma unroll
            for (int i = 0; i < 4; i++)
#pragma unroll
                for (int j = 0; j < 2; j++)
                    acc[i][j] = __builtin_amdgcn_mfma_f32_16x16x32_bf16(af[i], bfr[j], acc[i][j], 0, 0, 0);
        }
        __syncthreads();
    }
#pragma unroll
    for (int i = 0; i < 4; i++) {
        int row = m0 + wm * 64 + i * 16 + quad * 4;
#pragma unroll
        for (int j = 0; j < 2; j++) {
            int col = n0 + wn * 32 + j * 16 + l16;
#pragma unroll
            for (int r = 0; r < 4; r++) {
                size_t idx = (size_t)(row + r) * ldc + col;
                float v = acc[i][j][r];
                if (addC) v += addC[idx];
                C[idx] = v;
            }
        }
    }
}

// ------- conv(K=4) + SiLU + splits + dt prep + fused XT/BT transposes --------
#define LDW 1296                     // LDS row stride for slab (1288 + 8)
__global__ __launch_bounds__(256) void k_conv(const u16* __restrict__ zxb,
                                              const float* __restrict__ cw,
                                              const float* __restrict__ cb,
                                              const float* __restrict__ dt_bias,
                                              const float* __restrict__ A_log,
                                              u16* __restrict__ xsh, u16* __restrict__ Bsh,
                                              u16* __restrict__ Csh, u16* __restrict__ XT,
                                              u16* __restrict__ BT,
                                              float* __restrict__ dtp, float* __restrict__ laa) {
    int blk = blockIdx.x;                  // NROWS/TT = 512 blocks
    int b = blk / (LN_TOK / TT), tile = blk % (LN_TOK / TT);
    int t0 = tile * TT;
    int tid = threadIdx.x;
    __shared__ u16 ld[(TT + 3) * LDW];
    __shared__ float sv[TT][260];
    __shared__ u16 bcv[TT][132];

    for (int i = tid; i < (TT + 3) * 161; i += 256) {
        int r = i / 161, ch = (i % 161) * 8;
        int t = t0 - 3 + r;
        int4 v = make_int4(0, 0, 0, 0);
        if (t >= 0)
            v = *(const int4*)&zxb[((size_t)(b * LN_TOK + t)) * ZSTRIDE + DINNER + ch];
        *(int4*)&ld[r * LDW + ch] = v;
    }

    int cmap[5];
#pragma unroll
    for (int k = 0; k < 4; k++) cmap[k] = (tid >> 7) * 512 + (tid & 127) + 128 * k;
    cmap[4] = 1024 + tid;
    float w0[5], w1[5], w2[5], w3[5], bias[5];
#pragma unroll
    for (int k = 0; k < 5; k++) {
        int c = cmap[k];
        w0[k] = cw[c * 4 + 0]; w1[k] = cw[c * 4 + 1];
        w2[k] = cw[c * 4 + 2]; w3[k] = cw[c * 4 + 3];
        bias[k] = cb[c];
    }
    float dtb = 0.f, negA = 0.f;
    if (tid < NHEADS) { dtb = dt_bias[tid]; negA = -__expf(A_log[tid]); }

    __syncthreads();

    float h1[5], h2[5], h3[5];
#pragma unroll
    for (int k = 0; k < 5; k++) {
        h3[k] = b2f(ld[0 * LDW + cmap[k]]);
        h2[k] = b2f(ld[1 * LDW + cmap[k]]);
        h1[k] = b2f(ld[2 * LDW + cmap[k]]);
    }

    for (int m = 0; m < TT; m++) {
        int t = t0 + m;
        size_t rowp = (size_t)(b * LN_TOK + t) * GNN;
        float xpart = 0.f;
#pragma unroll
        for (int k = 0; k < 5; k++) {
            float cur = b2f(ld[(m + 3) * LDW + cmap[k]]);
            float conv = bias[k] + w3[k] * cur + w2[k] * h1[k] + w1[k] * h2[k] + w0[k] * h3[k];
            h3[k] = h2[k]; h2[k] = h1[k]; h1[k] = cur;
            float s = siluf_(conv);
            if (k < 4) xpart += s;
            else {
                u16 sb = f2b(s);
                if (tid < 128) { Bsh[rowp + tid] = sb; bcv[m][tid] = sb; }
                else           Csh[rowp + tid - 128] = sb;
            }
        }
        sv[m][tid] = xpart;
        if (tid < NHEADS) {
            float dtv = b2f(ld[(m + 3) * LDW + 1280 + tid]) + dtb;
            float dp = softplusf_(dtv);
            size_t idx = ((size_t)(b * NHEADS + tid)) * LN_TOK + t;
            dtp[idx] = dp;
            laa[idx] = negA * dp;
        }
    }
    __syncthreads();

    for (int idx = tid; idx < TT * 128; idx += 256) {
        int m = idx >> 7, p = idx & 127;
        xsh[(size_t)(b * LN_TOK + t0 + m) * GNN + p] =
            f2b((sv[m][p] + sv[m][p + 128]) * 0.125f);
    }
    {
        int p = tid & 127, tg = tid >> 7;
        u16 ox[8], ob[8];
#pragma unroll
        for (int j = 0; j < 8; j++) {
            int m = tg * 8 + j;
            ox[j] = f2b((sv[m][p] + sv[m][p + 128]) * 0.125f);
            ob[j] = bcv[m][p];
        }
        size_t base = ((size_t)(b * GNN + p)) * LN_TOK + t0 + tg * 8;
        int4 vx = make_int4((u32)ox[0] | ((u32)ox[1] << 16), (u32)ox[2] | ((u32)ox[3] << 16),
                            (u32)ox[4] | ((u32)ox[5] << 16), (u32)ox[6] | ((u32)ox[7] << 16));
        int4 vb = make_int4((u32)ob[0] | ((u32)ob[1] << 16), (u32)ob[2] | ((u32)ob[3] << 16),
                            (u32)ob[4] | ((u32)ob[5] << 16), (u32)ob[6] | ((u32)ob[7] << 16));
        *(int4*)&XT[base] = vx;
        *(int4*)&BT[base] = vb;
    }
}

// ---- chunkS: full-K staging (1 barrier per phase) + shuffle prefix scan -----
__global__ __launch_bounds__(256) void k_chunkS(const u16* __restrict__ BT,
                                                const u16* __restrict__ XT,
                                                const float* __restrict__ scale,
                                                const float* __restrict__ laa,
                                                const float* __restrict__ dtp,
                                                u16* __restrict__ states,
                                                float* __restrict__ gtot) {
    int blk = blockIdx.x;
    int c = blk & 31, h = (blk >> 5) & 7, b = blk >> 8;
    int t0 = c * CHUNK;
    __shared__ u16 As[128 * FPAD];      // scaled BT [n][s], full K
    __shared__ u16 Bs[128 * BKF];       // XT [p][s] via gld16, full K
    __shared__ float gsh[132], esc[128], scl[128];
    int tid = threadIdx.x;
    int wave = tid >> 6, lane = tid & 63;
    int wm = wave >> 1, wn = wave & 1;
    int quad = lane >> 4, l16 = lane & 15;
    size_t bhbase = (size_t)(b * NHEADS + h) * LN_TOK + t0;

    // ---- shuffle-based inclusive prefix of log-decay (3 barriers) ----
    float gv = (tid < 128) ? laa[bhbase + tid] : 0.f;
#pragma unroll
    for (int off = 1; off < 64; off <<= 1) {
        float v = __shfl_up(gv, off, 64);
        if (lane >= off) gv += v;
    }
    if (tid == 63) gsh[130] = gv;       // wave0 total
    __syncthreads();
    if (tid >= 64 && tid < 128) gv += gsh[130];
    if (tid < 128) gsh[tid] = gv;
    __syncthreads();
    float glast = gsh[127];
    if (tid < 128) {
        esc[tid] = __expf(glast - gsh[tid]) * dtp[bhbase + tid];
        scl[tid] = scale[h * GNN + tid];
    }
    if (tid == 0) gtot[(size_t)(b * NHEADS + h) * NCHUNK + c] = glast;
    __syncthreads();

    // ---- stage full K=128 (A VALU-scaled, B gld16), 1 barrier ----
    size_t tbase = (size_t)(b * GNN) * LN_TOK + t0;
#pragma unroll
    for (int p = 0; p < 8; p++) {
        int i = p * 256 + tid;
        int row = i >> 4, kk = (i & 15) << 3;
        gld16(&XT[tbase + (size_t)row * LN_TOK + kk], &Bs[i * 8]);
        int4 raw = *(const int4*)&BT[tbase + (size_t)row * LN_TOK + kk];
        u16* rp = (u16*)&raw;
        float sr = scl[row];
        u32 w[4];
#pragma unroll
        for (int q = 0; q < 4; q++) {
            u16 a  = f2b(b2f(rp[2 * q])     * sr * esc[kk + 2 * q]);
            u16 bb = f2b(b2f(rp[2 * q + 1]) * sr * esc[kk + 2 * q + 1]);
            w[q] = (u32)a | ((u32)bb << 16);
        }
        *(int4*)&As[row * FPAD + kk] = make_int4(w[0], w[1], w[2], w[3]);
    }
    __syncthreads();

    floatx4 acc[4][4] = {};
#pragma unroll
    for (int ks = 0; ks < 128; ks += 32) {
        shortx8 af[4], bfr[4];
#pragma unroll
        for (int i = 0; i < 4; i++)
            af[i] = *(shortx8*)&As[(wm * 64 + i * 16 + l16) * FPAD + ks + (quad << 3)];
#pragma unroll
        for (int j = 0; j < 4; j++)
            bfr[j] = *(shortx8*)&Bs[(wn * 64 + j * 16 + l16) * BKF + ks + (quad << 3)];
#pragma unroll
        for (int i = 0; i < 4; i++)
#pragma unroll
            for (int j = 0; j < 4; j++)
                acc[i][j] = __builtin_amdgcn_mfma_f32_16x16x32_bf16(af[i], bfr[j], acc[i][j], 0, 0, 0);
    }
    size_t sbase = (size_t)blk * 16384;
#pragma unroll
    for (int i = 0; i < 4; i++) {
        int n0 = wm * 64 + i * 16 + quad * 4;
#pragma unroll
        for (int j = 0; j < 4; j++) {
            int p = wn * 64 + j * 16 + l16;
            u16 o[4];
#pragma unroll
            for (int r = 0; r < 4; r++) o[r] = f2b(acc[i][j][r]);
            u32 lo = (u32)o[0] | ((u32)o[1] << 16);
            u32 hi = (u32)o[2] | ((u32)o[3] << 16);
            *(uint2*)&states[sbase + (size_t)p * CHUNK + n0] = make_uint2(lo, hi);
        }
    }
}

// ------ inter-chunk scan: 2 elems/thread, prefetched -------------------------
__global__ void k_scan(u16* __restrict__ states, const float* __restrict__ gtot) {
    int idx = blockIdx.x * 256 + threadIdx.x;   // 131072 threads
    int bh = idx >> 13;
    int np = (idx & 8191) * 2;
    __shared__ float sG[NCHUNK];
    if (threadIdx.x < NCHUNK) sG[threadIdx.x] = __expf(gtot[bh * NCHUNK + threadIdx.x]);
    __syncthreads();
    size_t base = (size_t)bh * NCHUNK * 16384 + np;
    float r0 = 0.f, r1 = 0.f;
    u32 v = *(u32*)&states[base];
    for (int c = 0; c < NCHUNK; c++) {
        u32 vn = (c < NCHUNK - 1) ? *(u32*)&states[base + (size_t)(c + 1) * 16384] : 0u;
        float l0 = b2f((u16)(v & 0xffff)), l1 = b2f((u16)(v >> 16));
        *(u32*)&states[base + (size_t)c * 16384] = (u32)f2b(r0) | ((u32)f2b(r1) << 16);
        float G = sG[c];
        r0 = G * r0 + l0; r1 = G * r1 + l1;
        v = vn;
    }
}

// ---- chunkMY2: full-K staging, MtAs union, shuffle prefix (9 barriers) ------
// GEMM1 (B'sc x Cs) -> Mt epilogue -> phase2 (Mt @ XT) -> phase1 (Cs*eg @ S0)
__global__ __launch_bounds__(256) void k_chunkMY2(const u16* __restrict__ Bsh,
                                                  const u16* __restrict__ Csh,
                                                  const float* __restrict__ scale,
                                                  const u16* __restrict__ states,
                                                  const u16* __restrict__ XT,
                                                  const float* __restrict__ laa,
                                                  const float* __restrict__ dtp,
                                                  u16* __restrict__ y) {
    int blk = blockIdx.x;
    int c = blk & 31, h = (blk >> 5) & 7, b = blk >> 8;
    int t0 = c * CHUNK;
    __shared__ u16 MtAs[128 * FPAD];    // union: full-K A panels / Mt (both stride FPAD)
    __shared__ u16 Bs[128 * BKF];       // full-K B via gld16
    __shared__ float gsh[132], eg[128], dts[128], sc[128];
    int tid = threadIdx.x;
    int wave = tid >> 6, lane = tid & 63;
    int wm = wave >> 1, wn = wave & 1;
    int quad = lane >> 4, l16 = lane & 15;
    size_t bhbase = (size_t)(b * NHEADS + h) * LN_TOK + t0;

    // ---- shuffle-based inclusive prefix ----
    float gv = (tid < 128) ? laa[bhbase + tid] : 0.f;
#pragma unroll
    for (int off = 1; off < 64; off <<= 1) {
        float v = __shfl_up(gv, off, 64);
        if (lane >= off) gv += v;
    }
    if (tid == 63) gsh[130] = gv;
    __syncthreads();
    if (tid >= 64 && tid < 128) gv += gsh[130];
    if (tid < 128) gsh[tid] = gv;
    __syncthreads();
    if (tid < 128) {
        eg[tid] = __expf(gsh[tid]);
        dts[tid] = dtp[bhbase + tid];
        sc[tid] = scale[h * GNN + tid];
    }
    __syncthreads();

    floatx4 acc[4][4] = {};
    size_t rbase = (size_t)(b * LN_TOK + t0) * GNN;
    // ---- GEMM1: A = Bsh*sc (rows s, K=n full), B = Csh (rows t) gld16 ----
#pragma unroll
    for (int p = 0; p < 8; p++) {
        int i = p * 256 + tid;
        int row = i >> 4, kk = (i & 15) << 3;
        gld16(&Csh[rbase + (size_t)row * GNN + kk], &Bs[i * 8]);
        int4 raw = *(const int4*)&Bsh[rbase + (size_t)row * GNN + kk];
        u16* rp = (u16*)&raw;
        u32 w[4];
#pragma unroll
        for (int q = 0; q < 4; q++) {
            u16 a  = f2b(b2f(rp[2 * q])     * sc[kk + 2 * q]);
            u16 bb = f2b(b2f(rp[2 * q + 1]) * sc[kk + 2 * q + 1]);
            w[q] = (u32)a | ((u32)bb << 16);
        }
        *(int4*)&MtAs[row * FPAD + kk] = make_int4(w[0], w[1], w[2], w[3]);
    }
    __syncthreads();
#pragma unroll
    for (int ks = 0; ks < 128; ks += 32) {
        shortx8 af[4], bfr[4];
#pragma unroll
        for (int i = 0; i < 4; i++)
            af[i] = *(shortx8*)&MtAs[(wm * 64 + i * 16 + l16) * FPAD + ks + (quad << 3)];
#pragma unroll
        for (int j = 0; j < 4; j++)
            bfr[j] = *(shortx8*)&Bs[(wn * 64 + j * 16 + l16) * BKF + ks + (quad << 3)];
#pragma unroll
        for (int i = 0; i < 4; i++)
#pragma unroll
            for (int j = 0; j < 4; j++)
                acc[i][j] = __builtin_amdgcn_mfma_f32_16x16x32_bf16(af[i], bfr[j], acc[i][j], 0, 0, 0);
    }
    __syncthreads();   // all waves done reading A panels before Mt overwrite
    // ---- masked decay -> Mt[t][s] (stride FPAD, overwrites A region) ----
#pragma unroll
    for (int i = 0; i < 4; i++) {
        int s0 = wm * 64 + i * 16 + quad * 4;
#pragma unroll
        for (int j = 0; j < 4; j++) {
            int t = wn * 64 + j * 16 + l16;
            u16 o[4];
#pragma unroll
            for (int r = 0; r < 4; r++) {
                int s = s0 + r;
                float v = (s <= t) ? acc[i][j][r] * __expf(gsh[t] - gsh[s]) * dts[s] : 0.f;
                o[r] = f2b(v);
            }
            u32 lo = (u32)o[0] | ((u32)o[1] << 16);
            u32 hi = (u32)o[2] | ((u32)o[3] << 16);
            *(uint2*)&MtAs[t * FPAD + s0] = make_uint2(lo, hi);
            acc[i][j] = (floatx4){0.f, 0.f, 0.f, 0.f};
        }
    }
    // ---- phase 2: A = Mt (rows t, K=s full), B = XT (rows p) gld16 ----
    size_t xtb = (size_t)(b * GNN) * LN_TOK + t0;
#pragma unroll
    for (int p = 0; p < 8; p++) {
        int i = p * 256 + tid;
        int row = i >> 4, kk = (i & 15) << 3;
        gld16(&XT[xtb + (size_t)row * LN_TOK + kk], &Bs[i * 8]);
    }
    __syncthreads();
#pragma unroll
    for (int ks = 0; ks < 128; ks += 32) {
        shortx8 af[4], bfr[4];
#pragma unroll
        for (int i = 0; i < 4; i++)
            af[i] = *(shortx8*)&MtAs[(wm * 64 + i * 16 + l16) * FPAD + ks + (quad << 3)];
#pragma unroll
        for (int j = 0; j < 4; j++)
            bfr[j] = *(shortx8*)&Bs[(wn * 64 + j * 16 + l16) * BKF + ks + (quad << 3)];
#pragma unroll
        for (int i = 0; i < 4; i++)
#pragma unroll
            for (int j = 0; j < 4; j++)
                acc[i][j] = __builtin_amdgcn_mfma_f32_16x16x32_bf16(af[i], bfr[j], acc[i][j], 0, 0, 0);
    }
    __syncthreads();   // done reading Mt / Bs
    // ---- phase 1: A = Csh*eg (rows t, K=n full), B = S0[p][n] gld16 ----
    size_t sbase = (size_t)blk * 16384;
#pragma unroll
    for (int p = 0; p < 8; p++) {
        int i = p * 256 + tid;
        int row = i >> 4, kk = (i & 15) << 3;
        gld16(&states[sbase + (size_t)row * CHUNK + kk], &Bs[i * 8]);
        int4 raw = *(const int4*)&Csh[rbase + (size_t)row * GNN + kk];
        float e = eg[row];
        u16* rp = (u16*)&raw;
        u32 w[4];
#pragma unroll
        for (int q = 0; q < 4; q++) {
            u16 a  = f2b(b2f(rp[2 * q]) * e);
            u16 bb = f2b(b2f(rp[2 * q + 1]) * e);
            w[q] = (u32)a | ((u32)bb << 16);
        }
        *(int4*)&MtAs[row * FPAD + kk] = make_int4(w[0], w[1], w[2], w[3]);
    }
    __syncthreads();
#pragma unroll
    for (int ks = 0; ks < 128; ks += 32) {
        shortx8 af[4], bfr[4];
#pragma unroll
        for (int i = 0; i < 4; i++)
            af[i] = *(shortx8*)&MtAs[(wm * 64 + i * 16 + l16) * FPAD + ks + (quad << 3)];
#pragma unroll
        for (int j = 0; j < 4; j++)
            bfr[j] = *(shortx8*)&Bs[(wn * 64 + j * 16 + l16) * BKF + ks + (quad << 3)];
#pragma unroll
        for (int i = 0; i < 4; i++)
#pragma unroll
            for (int j = 0; j < 4; j++)
                acc[i][j] = __builtin_amdgcn_mfma_f32_16x16x32_bf16(af[i], bfr[j], acc[i][j], 0, 0, 0);
    }
#pragma unroll
    for (int i = 0; i < 4; i++) {
        int t = wm * 64 + i * 16 + quad * 4;
#pragma unroll
        for (int j = 0; j < 4; j++) {
            int p = wn * 64 + j * 16 + l16;
#pragma unroll
            for (int r = 0; r < 4; r++)
                y[((size_t)(b * LN_TOK + t0 + t + r)) * DINNER + h * GNN + p] = f2b(acc[i][j][r]);
        }
    }
}

// ---------------- gating + D*x + RMSNorm -> bf16 ybuf ------------------------
__global__ void k_gate(const u16* __restrict__ y, const u16* __restrict__ zxb,
                       const u16* __restrict__ xsh, const float* __restrict__ Dp,
                       const float* __restrict__ rw, u16* __restrict__ ybuf) {
    int row = blockIdx.x;
    int tid = threadIdx.x;
    size_t yb = (size_t)row * DINNER;
    size_t zb = (size_t)row * ZSTRIDE;
    size_t xb = (size_t)row * GNN;
    float yg[4];
    float ss = 0.f;
#pragma unroll
    for (int q = 0; q < 4; q++) {
        int k = tid * 4 + q;
        int h = k >> 7, p = k & 127;
        float z = b2f(zxb[zb + k]);
        float v = (b2f(y[yb + k]) + Dp[h] * b2f(xsh[xb + p])) * z * sigmoidf_(z);
        yg[q] = v;
        ss += v * v;
    }
    __shared__ float red[256];
    red[tid] = ss;
    __syncthreads();
    for (int off = 128; off > 0; off >>= 1) {
        if (tid < off) red[tid] += red[tid + off];
        __syncthreads();
    }
    float scale = rsqrtf(red[0] * (1.f / DINNER) + EPSF);
#pragma unroll
    for (int q = 0; q < 4; q++) {
        int k = tid * 4 + q;
        ybuf[yb + k] = f2b(yg[q] * scale * rw[k]);
    }
}

extern "C" void kernel_launch(void* const* d_in, const int* in_sizes, int n_in,
                              void* d_out, int out_size, void* d_ws, size_t ws_size,
                              hipStream_t stream) {
    (void)in_sizes; (void)n_in; (void)out_size; (void)ws_size;
    const float* u        = (const float*)d_in[0];
    const float* ln_gamma = (const float*)d_in[1];
    const float* ln_beta  = (const float*)d_in[2];
    const float* W_in     = (const float*)d_in[3];
    const float* conv_w   = (const float*)d_in[4];
    const float* conv_b   = (const float*)d_in[5];
    const float* dt_bias  = (const float*)d_in[6];
    const float* A_log    = (const float*)d_in[7];
    const float* D_param  = (const float*)d_in[8];
    const float* B_scale  = (const float*)d_in[9];
    const float* rms_w    = (const float*)d_in[10];
    const float* W_out    = (const float*)d_in[11];
    float* out = (float*)d_out;

    char* ws = (char*)d_ws;
    u16*   xn_b   = (u16*)ws;                 ws += (size_t)NROWS * DMODEL * 2;
    u16*   Wt     = (u16*)ws;                 ws += (size_t)ZSTRIDE * DMODEL * 2;
    u16*   Wot    = (u16*)ws;                 ws += (size_t)DMODEL * DINNER * 2;
    u16*   zxb    = (u16*)ws;                 ws += (size_t)NROWS * ZSTRIDE * 2;
    u16*   xsh    = (u16*)ws;                 ws += (size_t)NROWS * GNN * 2;
    u16*   Bsh    = (u16*)ws;                 ws += (size_t)NROWS * GNN * 2;
    u16*   Csh    = (u16*)ws;                 ws += (size_t)NROWS * GNN * 2;
    u16*   XT     = (u16*)ws;                 ws += (size_t)NB * GNN * LN_TOK * 2;
    u16*   BT     = (u16*)ws;                 ws += (size_t)NB * GNN * LN_TOK * 2;
    float* dtp    = (float*)ws;               ws += (size_t)NB * NHEADS * LN_TOK * 4;
    float* laa    = (float*)ws;               ws += (size_t)NB * NHEADS * LN_TOK * 4;
    float* gtot   = (float*)ws;               ws += (size_t)NB * NHEADS * NCHUNK * 4;
    u16*   states = (u16*)ws;                 ws += (size_t)512 * 16384 * 2;
    u16*   ybig   = (u16*)ws;                 ws += (size_t)NROWS * DINNER * 2;
    u16*   ybuf   = (u16*)ws;                 ws += (size_t)NROWS * DINNER * 2;

    k_prologue<<<NROWS + 152 + 64, 256, 0, stream>>>(u, ln_gamma, ln_beta, xn_b,
                                                     W_in, Wt, W_out, Wot);

    k_gemm_bf<<<dim3(ZSTRIDE / 128, NROWS / 128), 256, 0, stream>>>(xn_b, Wt, zxb, DMODEL, ZSTRIDE);

    k_conv<<<NROWS / TT, 256, 0, stream>>>(zxb, conv_w, conv_b, dt_bias, A_log,
                                           xsh, Bsh, Csh, XT, BT, dtp, laa);

    k_chunkS<<<NB * NHEADS * NCHUNK, 256, 0, stream>>>(BT, XT, B_scale, laa, dtp, states, gtot);

    k_scan<<<512, 256, 0, stream>>>(states, gtot);

    k_chunkMY2<<<NB * NHEADS * NCHUNK, 256, 0, stream>>>(Bsh, Csh, B_scale, states,
                                                         XT, laa, dtp, ybig);

    k_gate<<<NROWS, 256, 0, stream>>>(ybig, zxb, xsh, D_param, rms_w, ybuf);

    k_gemm2<<<dim3(DMODEL / 64, NROWS / 128), 256, 0, stream>>>(ybuf, Wot, out, DINNER, DMODEL, u);
}

// Round 14
// 202.132 us; speedup vs baseline: 1.0735x; 1.0735x over previous
//
#include <hip/hip_runtime.h>
#include <math.h>

#define LN_TOK 4096
#define NB 2
#define NROWS (NB * LN_TOK)          // 8192
#define DMODEL 256
#define DINNER 1024
#define NHEADS 8
#define GNN 128
#define DPROJ 2312
#define ZSTRIDE 2432                 // padded in-proj N (19*128)
#define EPSF 1e-5f
#define NCHUNK 32
#define CHUNK 128
#define BPAD 64                      // LDS stride for gld16 staging (64-wide panels)
#define FPAD 136                     // LDS stride for full-K(128) VALU-staged A
#define BKF 128                      // LDS stride for full-K gld16 B
#define TT 16                        // conv tokens per block

typedef unsigned short u16;
typedef unsigned int u32;
typedef __attribute__((ext_vector_type(8))) short shortx8;
typedef __attribute__((ext_vector_type(4))) float floatx4;

__device__ __forceinline__ float sigmoidf_(float v) { return 1.f / (1.f + __expf(-v)); }
__device__ __forceinline__ float siluf_(float v)    { return v / (1.f + __expf(-v)); }
__device__ __forceinline__ float softplusf_(float v){ return v > 20.f ? v : log1pf(__expf(v)); }
__device__ __forceinline__ float b2f(u16 h) { return __uint_as_float(((u32)h) << 16); }
__device__ __forceinline__ u16 f2b(float f) {
    u32 u = __float_as_uint(f);
    u32 r = (u + 0x7fffu + ((u >> 16) & 1u)) >> 16;
    return (u16)r;
}
// async 16B global -> LDS (dest = wave-uniform base + lane*16)
__device__ __forceinline__ void gld16(const void* g, void* l) {
    __builtin_amdgcn_global_load_lds((const __attribute__((address_space(1))) unsigned int*)g,
                                     (__attribute__((address_space(3))) unsigned int*)l, 16, 0, 0);
}

// ------- prologue: LN (blocks 0..8191) + tcast W_in (next 152) + W_out (64) --
__global__ __launch_bounds__(256) void k_prologue(const float* __restrict__ u,
                                                  const float* __restrict__ gam,
                                                  const float* __restrict__ bet,
                                                  u16* __restrict__ xn,
                                                  const float* __restrict__ W_in,
                                                  u16* __restrict__ Wt,
                                                  const float* __restrict__ W_out,
                                                  u16* __restrict__ Wot) {
    __shared__ float smem[64 * 65];
    int bid = blockIdx.x;
    int tid = threadIdx.x;
    if (bid < NROWS) {
        float v = u[(size_t)bid * DMODEL + tid];
        float* s1 = smem;
        float* s2 = smem + 256;
        s1[tid] = v; s2[tid] = v * v;
        __syncthreads();
        for (int off = 128; off > 0; off >>= 1) {
            if (tid < off) { s1[tid] += s1[tid + off]; s2[tid] += s2[tid + off]; }
            __syncthreads();
        }
        float mean = s1[0] * (1.f / DMODEL);
        float var  = s2[0] * (1.f / DMODEL) - mean * mean;
        float r = rsqrtf(var + EPSF);
        xn[(size_t)bid * DMODEL + tid] = f2b((v - mean) * r * gam[tid] + bet[tid]);
    } else {
        const float* in; u16* outp; int R, C, Cp, gx, gy;
        if (bid < NROWS + 152) {
            int q = bid - NROWS;
            in = W_in; outp = Wt; R = DMODEL; C = DPROJ; Cp = ZSTRIDE;
            gx = q % (ZSTRIDE / 64); gy = q / (ZSTRIDE / 64);
        } else {
            int q = bid - NROWS - 152;
            in = W_out; outp = Wot; R = DINNER; C = DMODEL; Cp = DMODEL;
            gx = q % (DMODEL / 64); gy = q / (DMODEL / 64);
        }
        float (*tile)[65] = (float(*)[65])smem;
        int c0 = gx * 64, r0 = gy * 64;
        int tx = tid & 63, ty = tid >> 6;
        for (int rr = ty; rr < 64; rr += 4) {
            int r = r0 + rr, c = c0 + tx;
            tile[rr][tx] = (r < R && c < C) ? in[(size_t)r * C + c] : 0.f;
        }
        __syncthreads();
        for (int cc = ty; cc < 64; cc += 4) {
            int c = c0 + cc, r = r0 + tx;
            if (c < Cp && r < R) outp[(size_t)c * R + r] = f2b(tile[tx][cc]);
        }
    }
}

// ------- bf16 MFMA GEMM (bf16 out), 64x128 tile, pure gld16 staging ----------
// grid (N/128, M/64); 4 waves as 2(m) x 2(n); wave computes 32x64
__global__ __launch_bounds__(256) void k_gemm_bf(const u16* __restrict__ A,
                                                 const u16* __restrict__ Bt,
                                                 u16* __restrict__ C,
                                                 int K, int ldc) {
    __shared__ u16 As[64 * BPAD];
    __shared__ u16 Bs[128 * BPAD];
    int tid = threadIdx.x;
    int wave = tid >> 6, lane = tid & 63;
    int wm = wave >> 1, wn = wave & 1;
    int quad = lane >> 4, l16 = lane & 15;
    int m0 = blockIdx.y * 64, n0 = blockIdx.x * 128;
    floatx4 acc[2][4] = {};
    for (int k0 = 0; k0 < K; k0 += 64) {
#pragma unroll
        for (int p = 0; p < 2; p++) {
            int i = p * 256 + tid;
            int row = i >> 3, kk = (i & 7) << 3;
            gld16(&A[(size_t)(m0 + row) * K + k0 + kk], &As[i * 8]);
        }
#pragma unroll
        for (int p = 0; p < 4; p++) {
            int i = p * 256 + tid;
            int row = i >> 3, kk = (i & 7) << 3;
            gld16(&Bt[(size_t)(n0 + row) * K + k0 + kk], &Bs[i * 8]);
        }
        __syncthreads();
#pragma unroll
        for (int ks = 0; ks < 64; ks += 32) {
            shortx8 af[2], bfr[4];
#pragma unroll
            for (int i = 0; i < 2; i++)
                af[i] = *(shortx8*)&As[(wm * 32 + i * 16 + l16) * BPAD + ks + (quad << 3)];
#pragma unroll
            for (int j = 0; j < 4; j++)
                bfr[j] = *(shortx8*)&Bs[(wn * 64 + j * 16 + l16) * BPAD + ks + (quad << 3)];
#pragma unroll
            for (int i = 0; i < 2; i++)
#pragma unroll
                for (int j = 0; j < 4; j++)
                    acc[i][j] = __builtin_amdgcn_mfma_f32_16x16x32_bf16(af[i], bfr[j], acc[i][j], 0, 0, 0);
        }
        __syncthreads();
    }
#pragma unroll
    for (int i = 0; i < 2; i++) {
        int row = m0 + wm * 32 + i * 16 + quad * 4;
#pragma unroll
        for (int j = 0; j < 4; j++) {
            int col = n0 + wn * 64 + j * 16 + l16;
#pragma unroll
            for (int r = 0; r < 4; r++)
                C[(size_t)(row + r) * ldc + col] = f2b(acc[i][j][r]);
        }
    }
}

// ------- bf16 MFMA GEMM 64x64 tile, fp32 out + residual, pure gld16 ----------
// grid (N/64, M/64); 4 waves as 2x2; wave computes 32x32
__global__ __launch_bounds__(256) void k_gemm2(const u16* __restrict__ A,
                                               const u16* __restrict__ Bt,
                                               float* __restrict__ C,
                                               int K, int ldc,
                                               const float* __restrict__ addC) {
    __shared__ u16 As[64 * BPAD];
    __shared__ u16 Bs[64 * BPAD];
    int tid = threadIdx.x;
    int wave = tid >> 6, lane = tid & 63;
    int wm = wave >> 1, wn = wave & 1;
    int quad = lane >> 4, l16 = lane & 15;
    int m0 = blockIdx.y * 64, n0 = blockIdx.x * 64;
    floatx4 acc[2][2] = {};
    for (int k0 = 0; k0 < K; k0 += 64) {
#pragma unroll
        for (int p = 0; p < 2; p++) {
            int i = p * 256 + tid;
            int row = i >> 3, kk = (i & 7) << 3;
            gld16(&A[(size_t)(m0 + row) * K + k0 + kk], &As[i * 8]);
            gld16(&Bt[(size_t)(n0 + row) * K + k0 + kk], &Bs[i * 8]);
        }
        __syncthreads();
#pragma unroll
        for (int ks = 0; ks < 64; ks += 32) {
            shortx8 af[2], bfr[2];
#pragma unroll
            for (int i = 0; i < 2; i++)
                af[i] = *(shortx8*)&As[(wm * 32 + i * 16 + l16) * BPAD + ks + (quad << 3)];
#pragma unroll
            for (int j = 0; j < 2; j++)
                bfr[j] = *(shortx8*)&Bs[(wn * 32 + j * 16 + l16) * BPAD + ks + (quad << 3)];
#pragma unroll
            for (int i = 0; i < 2; i++)
#pragma unroll
                for (int j = 0; j < 2; j++)
                    acc[i][j] = __builtin_amdgcn_mfma_f32_16x16x32_bf16(af[i], bfr[j], acc[i][j], 0, 0, 0);
        }
        __syncthreads();
    }
#pragma unroll
    for (int i = 0; i < 2; i++) {
        int row = m0 + wm * 32 + i * 16 + quad * 4;
#pragma unroll
        for (int j = 0; j < 2; j++) {
            int col = n0 + wn * 32 + j * 16 + l16;
#pragma unroll
            for (int r = 0; r < 4; r++) {
                size_t idx = (size_t)(row + r) * ldc + col;
                float v = acc[i][j][r];
                if (addC) v += addC[idx];
                C[idx] = v;
            }
        }
    }
}

// ------- conv(K=4) + SiLU + splits + dt prep + fused XT/BT transposes --------
#define LDW 1296                     // LDS row stride for slab (1288 + 8)
__global__ __launch_bounds__(256) void k_conv(const u16* __restrict__ zxb,
                                              const float* __restrict__ cw,
                                              const float* __restrict__ cb,
                                              const float* __restrict__ dt_bias,
                                              const float* __restrict__ A_log,
                                              u16* __restrict__ xsh, u16* __restrict__ Bsh,
                                              u16* __restrict__ Csh, u16* __restrict__ XT,
                                              u16* __restrict__ BT,
                                              float* __restrict__ dtp, float* __restrict__ laa) {
    int blk = blockIdx.x;                  // NROWS/TT = 512 blocks
    int b = blk / (LN_TOK / TT), tile = blk % (LN_TOK / TT);
    int t0 = tile * TT;
    int tid = threadIdx.x;
    __shared__ u16 ld[(TT + 3) * LDW];
    __shared__ float sv[TT][260];
    __shared__ u16 bcv[TT][132];

    for (int i = tid; i < (TT + 3) * 161; i += 256) {
        int r = i / 161, ch = (i % 161) * 8;
        int t = t0 - 3 + r;
        int4 v = make_int4(0, 0, 0, 0);
        if (t >= 0)
            v = *(const int4*)&zxb[((size_t)(b * LN_TOK + t)) * ZSTRIDE + DINNER + ch];
        *(int4*)&ld[r * LDW + ch] = v;
    }

    int cmap[5];
#pragma unroll
    for (int k = 0; k < 4; k++) cmap[k] = (tid >> 7) * 512 + (tid & 127) + 128 * k;
    cmap[4] = 1024 + tid;
    float w0[5], w1[5], w2[5], w3[5], bias[5];
#pragma unroll
    for (int k = 0; k < 5; k++) {
        int c = cmap[k];
        w0[k] = cw[c * 4 + 0]; w1[k] = cw[c * 4 + 1];
        w2[k] = cw[c * 4 + 2]; w3[k] = cw[c * 4 + 3];
        bias[k] = cb[c];
    }
    float dtb = 0.f, negA = 0.f;
    if (tid < NHEADS) { dtb = dt_bias[tid]; negA = -__expf(A_log[tid]); }

    __syncthreads();

    float h1[5], h2[5], h3[5];
#pragma unroll
    for (int k = 0; k < 5; k++) {
        h3[k] = b2f(ld[0 * LDW + cmap[k]]);
        h2[k] = b2f(ld[1 * LDW + cmap[k]]);
        h1[k] = b2f(ld[2 * LDW + cmap[k]]);
    }

    for (int m = 0; m < TT; m++) {
        int t = t0 + m;
        size_t rowp = (size_t)(b * LN_TOK + t) * GNN;
        float xpart = 0.f;
#pragma unroll
        for (int k = 0; k < 5; k++) {
            float cur = b2f(ld[(m + 3) * LDW + cmap[k]]);
            float conv = bias[k] + w3[k] * cur + w2[k] * h1[k] + w1[k] * h2[k] + w0[k] * h3[k];
            h3[k] = h2[k]; h2[k] = h1[k]; h1[k] = cur;
            float s = siluf_(conv);
            if (k < 4) xpart += s;
            else {
                u16 sb = f2b(s);
                if (tid < 128) { Bsh[rowp + tid] = sb; bcv[m][tid] = sb; }
                else           Csh[rowp + tid - 128] = sb;
            }
        }
        sv[m][tid] = xpart;
        if (tid < NHEADS) {
            float dtv = b2f(ld[(m + 3) * LDW + 1280 + tid]) + dtb;
            float dp = softplusf_(dtv);
            size_t idx = ((size_t)(b * NHEADS + tid)) * LN_TOK + t;
            dtp[idx] = dp;
            laa[idx] = negA * dp;
        }
    }
    __syncthreads();

    for (int idx = tid; idx < TT * 128; idx += 256) {
        int m = idx >> 7, p = idx & 127;
        xsh[(size_t)(b * LN_TOK + t0 + m) * GNN + p] =
            f2b((sv[m][p] + sv[m][p + 128]) * 0.125f);
    }
    {
        int p = tid & 127, tg = tid >> 7;
        u16 ox[8], ob[8];
#pragma unroll
        for (int j = 0; j < 8; j++) {
            int m = tg * 8 + j;
            ox[j] = f2b((sv[m][p] + sv[m][p + 128]) * 0.125f);
            ob[j] = bcv[m][p];
        }
        size_t base = ((size_t)(b * GNN + p)) * LN_TOK + t0 + tg * 8;
        int4 vx = make_int4((u32)ox[0] | ((u32)ox[1] << 16), (u32)ox[2] | ((u32)ox[3] << 16),
                            (u32)ox[4] | ((u32)ox[5] << 16), (u32)ox[6] | ((u32)ox[7] << 16));
        int4 vb = make_int4((u32)ob[0] | ((u32)ob[1] << 16), (u32)ob[2] | ((u32)ob[3] << 16),
                            (u32)ob[4] | ((u32)ob[5] << 16), (u32)ob[6] | ((u32)ob[7] << 16));
        *(int4*)&XT[base] = vx;
        *(int4*)&BT[base] = vb;
    }
}

// ---- chunkS: full-K staging (1 barrier per phase) + shuffle prefix scan -----
__global__ __launch_bounds__(256) void k_chunkS(const u16* __restrict__ BT,
                                                const u16* __restrict__ XT,
                                                const float* __restrict__ scale,
                                                const float* __restrict__ laa,
                                                const float* __restrict__ dtp,
                                                u16* __restrict__ states,
                                                float* __restrict__ gtot) {
    int blk = blockIdx.x;
    int c = blk & 31, h = (blk >> 5) & 7, b = blk >> 8;
    int t0 = c * CHUNK;
    __shared__ u16 As[128 * FPAD];      // scaled BT [n][s], full K
    __shared__ u16 Bs[128 * BKF];       // XT [p][s] via gld16, full K
    __shared__ float gsh[132], esc[128], scl[128];
    int tid = threadIdx.x;
    int wave = tid >> 6, lane = tid & 63;
    int wm = wave >> 1, wn = wave & 1;
    int quad = lane >> 4, l16 = lane & 15;
    size_t bhbase = (size_t)(b * NHEADS + h) * LN_TOK + t0;

    float gv = (tid < 128) ? laa[bhbase + tid] : 0.f;
#pragma unroll
    for (int off = 1; off < 64; off <<= 1) {
        float v = __shfl_up(gv, off, 64);
        if (lane >= off) gv += v;
    }
    if (tid == 63) gsh[130] = gv;
    __syncthreads();
    if (tid >= 64 && tid < 128) gv += gsh[130];
    if (tid < 128) gsh[tid] = gv;
    __syncthreads();
    float glast = gsh[127];
    if (tid < 128) {
        esc[tid] = __expf(glast - gsh[tid]) * dtp[bhbase + tid];
        scl[tid] = scale[h * GNN + tid];
    }
    if (tid == 0) gtot[(size_t)(b * NHEADS + h) * NCHUNK + c] = glast;
    __syncthreads();

    size_t tbase = (size_t)(b * GNN) * LN_TOK + t0;
#pragma unroll
    for (int p = 0; p < 8; p++) {
        int i = p * 256 + tid;
        int row = i >> 4, kk = (i & 15) << 3;
        gld16(&XT[tbase + (size_t)row * LN_TOK + kk], &Bs[i * 8]);
        int4 raw = *(const int4*)&BT[tbase + (size_t)row * LN_TOK + kk];
        u16* rp = (u16*)&raw;
        float sr = scl[row];
        u32 w[4];
#pragma unroll
        for (int q = 0; q < 4; q++) {
            u16 a  = f2b(b2f(rp[2 * q])     * sr * esc[kk + 2 * q]);
            u16 bb = f2b(b2f(rp[2 * q + 1]) * sr * esc[kk + 2 * q + 1]);
            w[q] = (u32)a | ((u32)bb << 16);
        }
        *(int4*)&As[row * FPAD + kk] = make_int4(w[0], w[1], w[2], w[3]);
    }
    __syncthreads();

    floatx4 acc[4][4] = {};
#pragma unroll
    for (int ks = 0; ks < 128; ks += 32) {
        shortx8 af[4], bfr[4];
#pragma unroll
        for (int i = 0; i < 4; i++)
            af[i] = *(shortx8*)&As[(wm * 64 + i * 16 + l16) * FPAD + ks + (quad << 3)];
#pragma unroll
        for (int j = 0; j < 4; j++)
            bfr[j] = *(shortx8*)&Bs[(wn * 64 + j * 16 + l16) * BKF + ks + (quad << 3)];
#pragma unroll
        for (int i = 0; i < 4; i++)
#pragma unroll
            for (int j = 0; j < 4; j++)
                acc[i][j] = __builtin_amdgcn_mfma_f32_16x16x32_bf16(af[i], bfr[j], acc[i][j], 0, 0, 0);
    }
    size_t sbase = (size_t)blk * 16384;
#pragma unroll
    for (int i = 0; i < 4; i++) {
        int n0 = wm * 64 + i * 16 + quad * 4;
#pragma unroll
        for (int j = 0; j < 4; j++) {
            int p = wn * 64 + j * 16 + l16;
            u16 o[4];
#pragma unroll
            for (int r = 0; r < 4; r++) o[r] = f2b(acc[i][j][r]);
            u32 lo = (u32)o[0] | ((u32)o[1] << 16);
            u32 hi = (u32)o[2] | ((u32)o[3] << 16);
            *(uint2*)&states[sbase + (size_t)p * CHUNK + n0] = make_uint2(lo, hi);
        }
    }
}

// ------ inter-chunk scan: 2 elems/thread, prefetched -------------------------
__global__ void k_scan(u16* __restrict__ states, const float* __restrict__ gtot) {
    int idx = blockIdx.x * 256 + threadIdx.x;   // 131072 threads
    int bh = idx >> 13;
    int np = (idx & 8191) * 2;
    __shared__ float sG[NCHUNK];
    if (threadIdx.x < NCHUNK) sG[threadIdx.x] = __expf(gtot[bh * NCHUNK + threadIdx.x]);
    __syncthreads();
    size_t base = (size_t)bh * NCHUNK * 16384 + np;
    float r0 = 0.f, r1 = 0.f;
    u32 v = *(u32*)&states[base];
    for (int c = 0; c < NCHUNK; c++) {
        u32 vn = (c < NCHUNK - 1) ? *(u32*)&states[base + (size_t)(c + 1) * 16384] : 0u;
        float l0 = b2f((u16)(v & 0xffff)), l1 = b2f((u16)(v >> 16));
        *(u32*)&states[base + (size_t)c * 16384] = (u32)f2b(r0) | ((u32)f2b(r1) << 16);
        float G = sG[c];
        r0 = G * r0 + l0; r1 = G * r1 + l1;
        v = vn;
    }
}

// ---- chunkMY2: full-K staging, MtAs union, shuffle prefix -------------------
// GEMM1 (B'sc x Cs) -> Mt epilogue -> phase2 (Mt @ XT) -> phase1 (Cs*eg @ S0)
__global__ __launch_bounds__(256) void k_chunkMY2(const u16* __restrict__ Bsh,
                                                  const u16* __restrict__ Csh,
                                                  const float* __restrict__ scale,
                                                  const u16* __restrict__ states,
                                                  const u16* __restrict__ XT,
                                                  const float* __restrict__ laa,
                                                  const float* __restrict__ dtp,
                                                  u16* __restrict__ y) {
    int blk = blockIdx.x;
    int c = blk & 31, h = (blk >> 5) & 7, b = blk >> 8;
    int t0 = c * CHUNK;
    __shared__ u16 MtAs[128 * FPAD];    // union: full-K A panels / Mt (both stride FPAD)
    __shared__ u16 Bs[128 * BKF];       // full-K B via gld16
    __shared__ float gsh[132], eg[128], dts[128], sc[128];
    int tid = threadIdx.x;
    int wave = tid >> 6, lane = tid & 63;
    int wm = wave >> 1, wn = wave & 1;
    int quad = lane >> 4, l16 = lane & 15;
    size_t bhbase = (size_t)(b * NHEADS + h) * LN_TOK + t0;

    float gv = (tid < 128) ? laa[bhbase + tid] : 0.f;
#pragma unroll
    for (int off = 1; off < 64; off <<= 1) {
        float v = __shfl_up(gv, off, 64);
        if (lane >= off) gv += v;
    }
    if (tid == 63) gsh[130] = gv;
    __syncthreads();
    if (tid >= 64 && tid < 128) gv += gsh[130];
    if (tid < 128) gsh[tid] = gv;
    __syncthreads();
    if (tid < 128) {
        eg[tid] = __expf(gsh[tid]);
        dts[tid] = dtp[bhbase + tid];
        sc[tid] = scale[h * GNN + tid];
    }
    __syncthreads();

    floatx4 acc[4][4] = {};
    size_t rbase = (size_t)(b * LN_TOK + t0) * GNN;
    // ---- GEMM1: A = Bsh*sc (rows s, K=n full), B = Csh (rows t) gld16 ----
#pragma unroll
    for (int p = 0; p < 8; p++) {
        int i = p * 256 + tid;
        int row = i >> 4, kk = (i & 15) << 3;
        gld16(&Csh[rbase + (size_t)row * GNN + kk], &Bs[i * 8]);
        int4 raw = *(const int4*)&Bsh[rbase + (size_t)row * GNN + kk];
        u16* rp = (u16*)&raw;
        u32 w[4];
#pragma unroll
        for (int q = 0; q < 4; q++) {
            u16 a  = f2b(b2f(rp[2 * q])     * sc[kk + 2 * q]);
            u16 bb = f2b(b2f(rp[2 * q + 1]) * sc[kk + 2 * q + 1]);
            w[q] = (u32)a | ((u32)bb << 16);
        }
        *(int4*)&MtAs[row * FPAD + kk] = make_int4(w[0], w[1], w[2], w[3]);
    }
    __syncthreads();
#pragma unroll
    for (int ks = 0; ks < 128; ks += 32) {
        shortx8 af[4], bfr[4];
#pragma unroll
        for (int i = 0; i < 4; i++)
            af[i] = *(shortx8*)&MtAs[(wm * 64 + i * 16 + l16) * FPAD + ks + (quad << 3)];
#pragma unroll
        for (int j = 0; j < 4; j++)
            bfr[j] = *(shortx8*)&Bs[(wn * 64 + j * 16 + l16) * BKF + ks + (quad << 3)];
#pragma unroll
        for (int i = 0; i < 4; i++)
#pragma unroll
            for (int j = 0; j < 4; j++)
                acc[i][j] = __builtin_amdgcn_mfma_f32_16x16x32_bf16(af[i], bfr[j], acc[i][j], 0, 0, 0);
    }
    __syncthreads();   // all waves done reading A panels before Mt overwrite
    // ---- masked decay -> Mt[t][s] (stride FPAD, overwrites A region) ----
#pragma unroll
    for (int i = 0; i < 4; i++) {
        int s0 = wm * 64 + i * 16 + quad * 4;
#pragma unroll
        for (int j = 0; j < 4; j++) {
            int t = wn * 64 + j * 16 + l16;
            u16 o[4];
#pragma unroll
            for (int r = 0; r < 4; r++) {
                int s = s0 + r;
                float v = (s <= t) ? acc[i][j][r] * __expf(gsh[t] - gsh[s]) * dts[s] : 0.f;
                o[r] = f2b(v);
            }
            u32 lo = (u32)o[0] | ((u32)o[1] << 16);
            u32 hi = (u32)o[2] | ((u32)o[3] << 16);
            *(uint2*)&MtAs[t * FPAD + s0] = make_uint2(lo, hi);
            acc[i][j] = (floatx4){0.f, 0.f, 0.f, 0.f};
        }
    }
    // ---- phase 2: A = Mt (rows t, K=s full), B = XT (rows p) gld16 ----
    size_t xtb = (size_t)(b * GNN) * LN_TOK + t0;
#pragma unroll
    for (int p = 0; p < 8; p++) {
        int i = p * 256 + tid;
        int row = i >> 4, kk = (i & 15) << 3;
        gld16(&XT[xtb + (size_t)row * LN_TOK + kk], &Bs[i * 8]);
    }
    __syncthreads();
#pragma unroll
    for (int ks = 0; ks < 128; ks += 32) {
        shortx8 af[4], bfr[4];
#pragma unroll
        for (int i = 0; i < 4; i++)
            af[i] = *(shortx8*)&MtAs[(wm * 64 + i * 16 + l16) * FPAD + ks + (quad << 3)];
#pragma unroll
        for (int j = 0; j < 4; j++)
            bfr[j] = *(shortx8*)&Bs[(wn * 64 + j * 16 + l16) * BKF + ks + (quad << 3)];
#pragma unroll
        for (int i = 0; i < 4; i++)
#pragma unroll
            for (int j = 0; j < 4; j++)
                acc[i][j] = __builtin_amdgcn_mfma_f32_16x16x32_bf16(af[i], bfr[j], acc[i][j], 0, 0, 0);
    }
    __syncthreads();   // done reading Mt / Bs
    // ---- phase 1: A = Csh*eg (rows t, K=n full), B = S0[p][n] gld16 ----
    size_t sbase = (size_t)blk * 16384;
#pragma unroll
    for (int p = 0; p < 8; p++) {
        int i = p * 256 + tid;
        int row = i >> 4, kk = (i & 15) << 3;
        gld16(&states[sbase + (size_t)row * CHUNK + kk], &Bs[i * 8]);
        int4 raw = *(const int4*)&Csh[rbase + (size_t)row * GNN + kk];
        float e = eg[row];
        u16* rp = (u16*)&raw;
        u32 w[4];
#pragma unroll
        for (int q = 0; q < 4; q++) {
            u16 a  = f2b(b2f(rp[2 * q]) * e);
            u16 bb = f2b(b2f(rp[2 * q + 1]) * e);
            w[q] = (u32)a | ((u32)bb << 16);
        }
        *(int4*)&MtAs[row * FPAD + kk] = make_int4(w[0], w[1], w[2], w[3]);
    }
    __syncthreads();
#pragma unroll
    for (int ks = 0; ks < 128; ks += 32) {
        shortx8 af[4], bfr[4];
#pragma unroll
        for (int i = 0; i < 4; i++)
            af[i] = *(shortx8*)&MtAs[(wm * 64 + i * 16 + l16) * FPAD + ks + (quad << 3)];
#pragma unroll
        for (int j = 0; j < 4; j++)
            bfr[j] = *(shortx8*)&Bs[(wn * 64 + j * 16 + l16) * BKF + ks + (quad << 3)];
#pragma unroll
        for (int i = 0; i < 4; i++)
#pragma unroll
            for (int j = 0; j < 4; j++)
                acc[i][j] = __builtin_amdgcn_mfma_f32_16x16x32_bf16(af[i], bfr[j], acc[i][j], 0, 0, 0);
    }
#pragma unroll
    for (int i = 0; i < 4; i++) {
        int t = wm * 64 + i * 16 + quad * 4;
#pragma unroll
        for (int j = 0; j < 4; j++) {
            int p = wn * 64 + j * 16 + l16;
#pragma unroll
            for (int r = 0; r < 4; r++)
                y[((size_t)(b * LN_TOK + t0 + t + r)) * DINNER + h * GNN + p] = f2b(acc[i][j][r]);
        }
    }
}

// ---------------- gating + D*x + RMSNorm -> bf16 ybuf ------------------------
__global__ void k_gate(const u16* __restrict__ y, const u16* __restrict__ zxb,
                       const u16* __restrict__ xsh, const float* __restrict__ Dp,
                       const float* __restrict__ rw, u16* __restrict__ ybuf) {
    int row = blockIdx.x;
    int tid = threadIdx.x;
    size_t yb = (size_t)row * DINNER;
    size_t zb = (size_t)row * ZSTRIDE;
    size_t xb = (size_t)row * GNN;
    float yg[4];
    float ss = 0.f;
#pragma unroll
    for (int q = 0; q < 4; q++) {
        int k = tid * 4 + q;
        int h = k >> 7, p = k & 127;
        float z = b2f(zxb[zb + k]);
        float v = (b2f(y[yb + k]) + Dp[h] * b2f(xsh[xb + p])) * z * sigmoidf_(z);
        yg[q] = v;
        ss += v * v;
    }
    __shared__ float red[256];
    red[tid] = ss;
    __syncthreads();
    for (int off = 128; off > 0; off >>= 1) {
        if (tid < off) red[tid] += red[tid + off];
        __syncthreads();
    }
    float scale = rsqrtf(red[0] * (1.f / DINNER) + EPSF);
#pragma unroll
    for (int q = 0; q < 4; q++) {
        int k = tid * 4 + q;
        ybuf[yb + k] = f2b(yg[q] * scale * rw[k]);
    }
}

extern "C" void kernel_launch(void* const* d_in, const int* in_sizes, int n_in,
                              void* d_out, int out_size, void* d_ws, size_t ws_size,
                              hipStream_t stream) {
    (void)in_sizes; (void)n_in; (void)out_size; (void)ws_size;
    const float* u        = (const float*)d_in[0];
    const float* ln_gamma = (const float*)d_in[1];
    const float* ln_beta  = (const float*)d_in[2];
    const float* W_in     = (const float*)d_in[3];
    const float* conv_w   = (const float*)d_in[4];
    const float* conv_b   = (const float*)d_in[5];
    const float* dt_bias  = (const float*)d_in[6];
    const float* A_log    = (const float*)d_in[7];
    const float* D_param  = (const float*)d_in[8];
    const float* B_scale  = (const float*)d_in[9];
    const float* rms_w    = (const float*)d_in[10];
    const float* W_out    = (const float*)d_in[11];
    float* out = (float*)d_out;

    char* ws = (char*)d_ws;
    u16*   xn_b   = (u16*)ws;                 ws += (size_t)NROWS * DMODEL * 2;
    u16*   Wt     = (u16*)ws;                 ws += (size_t)ZSTRIDE * DMODEL * 2;
    u16*   Wot    = (u16*)ws;                 ws += (size_t)DMODEL * DINNER * 2;
    u16*   zxb    = (u16*)ws;                 ws += (size_t)NROWS * ZSTRIDE * 2;
    u16*   xsh    = (u16*)ws;                 ws += (size_t)NROWS * GNN * 2;
    u16*   Bsh    = (u16*)ws;                 ws += (size_t)NROWS * GNN * 2;
    u16*   Csh    = (u16*)ws;                 ws += (size_t)NROWS * GNN * 2;
    u16*   XT     = (u16*)ws;                 ws += (size_t)NB * GNN * LN_TOK * 2;
    u16*   BT     = (u16*)ws;                 ws += (size_t)NB * GNN * LN_TOK * 2;
    float* dtp    = (float*)ws;               ws += (size_t)NB * NHEADS * LN_TOK * 4;
    float* laa    = (float*)ws;               ws += (size_t)NB * NHEADS * LN_TOK * 4;
    float* gtot   = (float*)ws;               ws += (size_t)NB * NHEADS * NCHUNK * 4;
    u16*   states = (u16*)ws;                 ws += (size_t)512 * 16384 * 2;
    u16*   ybig   = (u16*)ws;                 ws += (size_t)NROWS * DINNER * 2;
    u16*   ybuf   = (u16*)ws;                 ws += (size_t)NROWS * DINNER * 2;

    k_prologue<<<NROWS + 152 + 64, 256, 0, stream>>>(u, ln_gamma, ln_beta, xn_b,
                                                     W_in, Wt, W_out, Wot);

    k_gemm_bf<<<dim3(ZSTRIDE / 128, NROWS / 64), 256, 0, stream>>>(xn_b, Wt, zxb, DMODEL, ZSTRIDE);

    k_conv<<<NROWS / TT, 256, 0, stream>>>(zxb, conv_w, conv_b, dt_bias, A_log,
                                           xsh, Bsh, Csh, XT, BT, dtp, laa);

    k_chunkS<<<NB * NHEADS * NCHUNK, 256, 0, stream>>>(BT, XT, B_scale, laa, dtp, states, gtot);

    k_scan<<<512, 256, 0, stream>>>(states, gtot);

    k_chunkMY2<<<NB * NHEADS * NCHUNK, 256, 0, stream>>>(Bsh, Csh, B_scale, states,
                                                         XT, laa, dtp, ybig);

    k_gate<<<NROWS, 256, 0, stream>>>(ybig, zxb, xsh, D_param, rms_w, ybuf);

    k_gemm2<<<dim3(DMODEL / 64, NROWS / 64), 256, 0, stream>>>(ybuf, Wot, out, DINNER, DMODEL, u);
}